// Round 1
// baseline (424.662 us; speedup 1.0000x reference)
//
#include <hip/hip_runtime.h>

#define M_DIM 8192
#define N_DIM 4096
#define K_DIM 4096

typedef __bf16 bf16x8 __attribute__((ext_vector_type(8)));
typedef float f32x4 __attribute__((ext_vector_type(4)));

// bf16 round-to-nearest-even from fp32 (no NaN in this problem)
__device__ __forceinline__ unsigned short f2bf(float f) {
    unsigned u = __float_as_uint(f);
    u += 0x7FFFu + ((u >> 16) & 1u);
    return (unsigned short)(u >> 16);
}

// Bit-exact replica of reference _cast_e4m3 (round-half-even, subnormals, sat 448)
__device__ __forceinline__ float cast_e4m3(float v) {
    float a = fminf(fabsf(v), 448.0f);
    float am = fmaxf(a, 0x1p-9f);
    int e = (int)((__float_as_uint(am) >> 23) & 0xFFu) - 127;   // floor(log2(am)), exact
    e = (e < -6) ? -6 : e;
    float step = __uint_as_float((unsigned)(e - 3 + 127) << 23); // 2^(e-3)
    float q = rintf(a / step) * step;                            // a/step exact, RNE tie
    q = fminf(q, 448.0f);
    return (v < 0.0f) ? -q : q;
}

// x: per-row 1x128 blocks. One 32-lane group per block, 4 floats/lane.
__global__ __launch_bounds__(256) void quant_x(const float* __restrict__ X,
                                               unsigned short* __restrict__ Xq) {
    const int g = threadIdx.x >> 5;           // 0..7 half-wave groups
    const int l = threadIdx.x & 31;
    const long rb = (long)blockIdx.x * 8 + g; // row-block id, 8192*32 total
    const int row = (int)(rb >> 5);
    const int kb = (int)(rb & 31);
    const size_t base = (size_t)row * K_DIM + kb * 128 + l * 4;
    const float4 v = *(const float4*)&X[base];
    float amax = fmaxf(fmaxf(fabsf(v.x), fabsf(v.y)), fmaxf(fabsf(v.z), fabsf(v.w)));
    #pragma unroll
    for (int m = 16; m >= 1; m >>= 1)
        amax = fmaxf(amax, __shfl_xor(amax, m));   // stays within 32-lane half
    const float scale = fmaxf(amax, 1e-12f) / 448.0f;
    ushort4 o;
    o.x = f2bf(cast_e4m3(v.x / scale) * scale);
    o.y = f2bf(cast_e4m3(v.y / scale) * scale);
    o.z = f2bf(cast_e4m3(v.z / scale) * scale);
    o.w = f2bf(cast_e4m3(v.w / scale) * scale);
    *(ushort4*)&Xq[base] = o;
}

// w: 128x128 tiles. One 256-thread block per tile; values held in registers.
__global__ __launch_bounds__(256) void quant_w(const float* __restrict__ W,
                                               unsigned short* __restrict__ Wq) {
    const int tile = blockIdx.x;
    const int tr = tile >> 5;           // N/128 = 32
    const int tc = tile & 31;           // K/128 = 32
    const int t = threadIdx.x;
    const int c4 = (t & 31) * 4;
    const float* base = W + (size_t)(tr * 128) * K_DIM + tc * 128;

    float4 v[16];
    float amax = 0.0f;
    #pragma unroll
    for (int p = 0; p < 16; ++p) {
        const int r = p * 8 + (t >> 5);
        v[p] = *(const float4*)&base[(size_t)r * K_DIM + c4];
        amax = fmaxf(amax, fmaxf(fmaxf(fabsf(v[p].x), fabsf(v[p].y)),
                                 fmaxf(fabsf(v[p].z), fabsf(v[p].w))));
    }
    #pragma unroll
    for (int m = 32; m >= 1; m >>= 1)
        amax = fmaxf(amax, __shfl_xor(amax, m));
    __shared__ float red[4];
    if ((t & 63) == 0) red[t >> 6] = amax;
    __syncthreads();
    const float am4 = fmaxf(fmaxf(red[0], red[1]), fmaxf(red[2], red[3]));
    const float scale = fmaxf(am4, 1e-12f) / 448.0f;

    unsigned short* out = Wq + (size_t)(tr * 128) * K_DIM + tc * 128;
    #pragma unroll
    for (int p = 0; p < 16; ++p) {
        const int r = p * 8 + (t >> 5);
        ushort4 o;
        o.x = f2bf(cast_e4m3(v[p].x / scale) * scale);
        o.y = f2bf(cast_e4m3(v[p].y / scale) * scale);
        o.z = f2bf(cast_e4m3(v[p].z / scale) * scale);
        o.w = f2bf(cast_e4m3(v[p].w / scale) * scale);
        *(ushort4*)&out[(size_t)r * K_DIM + c4] = o;
    }
}

#define GLOAD16(g, l)                                                          \
    __builtin_amdgcn_global_load_lds(                                          \
        (const __attribute__((address_space(1))) void*)(g),                    \
        (__attribute__((address_space(3))) void*)(l), 16, 0, 0)

// C[M,N] = A[M,K] * B[N,K]^T + bias   (bf16 in, fp32 out). 128x128 tile, BK=32.
__global__ __launch_bounds__(256) void gemm_bt(const unsigned short* __restrict__ A,
                                               const unsigned short* __restrict__ B,
                                               const float* __restrict__ bias,
                                               float* __restrict__ C) {
    __shared__ __align__(16) unsigned short As[128 * 32];
    __shared__ __align__(16) unsigned short Bs[128 * 32];

    const int t = threadIdx.x;
    const int wave = t >> 6;
    const int lane = t & 63;

    // bijective XCD swizzle (nwg = 2048, divisible by 8)
    int bid = blockIdx.x;
    const int cpx = (M_DIM / 128) * (N_DIM / 128) / 8;
    bid = (bid & 7) * cpx + (bid >> 3);
    const int bn = bid & (N_DIM / 128 - 1);
    const int bm = bid >> 5;

    const size_t brow = (size_t)bm * 128;
    const size_t bcol = (size_t)bn * 128;

    const int wr = (wave >> 1) * 64;
    const int wc = (wave & 1) * 64;
    const int lr = lane & 15;
    const int lk = (lane >> 4) * 8;

    // staging: thread t loads 16B; rows t/4, col-group t%4 (8 bf16)
    const int srow = t >> 2;
    const int scol = (t & 3) * 8;
    const unsigned short* ga0 = A + (brow + srow) * K_DIM + scol;
    const unsigned short* ga1 = A + (brow + 64 + srow) * K_DIM + scol;
    const unsigned short* gb0 = B + (bcol + srow) * K_DIM + scol;
    const unsigned short* gb1 = B + (bcol + 64 + srow) * K_DIM + scol;
    char* lAs = (char*)As + wave * 1024;   // wave-uniform; HW adds lane*16
    char* lBs = (char*)Bs + wave * 1024;

    f32x4 acc[4][4] = {};

    for (int k0 = 0; k0 < K_DIM; k0 += 32) {
        GLOAD16(ga0 + k0, lAs);
        GLOAD16(ga1 + k0, lAs + 4096);
        GLOAD16(gb0 + k0, lBs);
        GLOAD16(gb1 + k0, lBs + 4096);
        __syncthreads();   // drains vmcnt(0) then barrier

        bf16x8 af[4], bg[4];
        #pragma unroll
        for (int m = 0; m < 4; ++m)
            af[m] = *(const bf16x8*)&As[(wr + m * 16 + lr) * 32 + lk];
        #pragma unroll
        for (int n = 0; n < 4; ++n)
            bg[n] = *(const bf16x8*)&Bs[(wc + n * 16 + lr) * 32 + lk];
        #pragma unroll
        for (int m = 0; m < 4; ++m)
            #pragma unroll
            for (int n = 0; n < 4; ++n)
                acc[m][n] = __builtin_amdgcn_mfma_f32_16x16x32_bf16(
                    af[m], bg[n], acc[m][n], 0, 0, 0);
        __syncthreads();   // all waves done reading before next stage
    }

    // C/D layout: col = lane&15, row = (lane>>4)*4 + reg  [m89/m91 verified]
    #pragma unroll
    for (int m = 0; m < 4; ++m) {
        const size_t row_base = brow + wr + m * 16 + (lane >> 4) * 4;
        #pragma unroll
        for (int n = 0; n < 4; ++n) {
            const size_t col = bcol + wc + n * 16 + (lane & 15);
            const float bv = bias[col];
            #pragma unroll
            for (int j = 0; j < 4; ++j)
                C[(row_base + j) * (size_t)N_DIM + col] = acc[m][n][j] + bv;
        }
    }
}

extern "C" void kernel_launch(void* const* d_in, const int* in_sizes, int n_in,
                              void* d_out, int out_size, void* d_ws, size_t ws_size,
                              hipStream_t stream) {
    const float* x = (const float*)d_in[0];
    const float* w = (const float*)d_in[1];
    const float* bias = (const float*)d_in[2];
    float* out = (float*)d_out;

    unsigned short* xq = (unsigned short*)d_ws;                     // 8192*4096 bf16 = 64 MiB
    unsigned short* wq = xq + (size_t)M_DIM * K_DIM;                // 4096*4096 bf16 = 32 MiB

    quant_x<<<(M_DIM * (K_DIM / 128)) / 8, 256, 0, stream>>>(x, xq);
    quant_w<<<(N_DIM / 128) * (K_DIM / 128), 256, 0, stream>>>(w, wq);
    gemm_bt<<<(M_DIM / 128) * (N_DIM / 128), 256, 0, stream>>>(xq, wq, bias, out);
}

// Round 2
// 308.658 us; speedup vs baseline: 1.3758x; 1.3758x over previous
//
#include <hip/hip_runtime.h>

#define M_DIM 8192
#define N_DIM 4096
#define K_DIM 4096

typedef __bf16 bf16x8 __attribute__((ext_vector_type(8)));
typedef float f32x4 __attribute__((ext_vector_type(4)));

// bf16 round-to-nearest-even from fp32 (no NaN in this problem)
__device__ __forceinline__ unsigned short f2bf(float f) {
    unsigned u = __float_as_uint(f);
    u += 0x7FFFu + ((u >> 16) & 1u);
    return (unsigned short)(u >> 16);
}

// Bit-exact replica of reference _cast_e4m3 (round-half-even, subnormals, sat 448)
__device__ __forceinline__ float cast_e4m3(float v) {
    float a = fminf(fabsf(v), 448.0f);
    float am = fmaxf(a, 0x1p-9f);
    int e = (int)((__float_as_uint(am) >> 23) & 0xFFu) - 127;   // floor(log2(am)), exact
    e = (e < -6) ? -6 : e;
    float step = __uint_as_float((unsigned)(e - 3 + 127) << 23); // 2^(e-3)
    float q = rintf(a / step) * step;                            // a/step exact, RNE tie
    q = fminf(q, 448.0f);
    return (v < 0.0f) ? -q : q;
}

// x: per-row 1x128 blocks. One 32-lane group per block, 4 floats/lane.
__global__ __launch_bounds__(256) void quant_x(const float* __restrict__ X,
                                               unsigned short* __restrict__ Xq) {
    const int g = threadIdx.x >> 5;
    const int l = threadIdx.x & 31;
    const long rb = (long)blockIdx.x * 8 + g;
    const int row = (int)(rb >> 5);
    const int kb = (int)(rb & 31);
    const size_t base = (size_t)row * K_DIM + kb * 128 + l * 4;
    const float4 v = *(const float4*)&X[base];
    float amax = fmaxf(fmaxf(fabsf(v.x), fabsf(v.y)), fmaxf(fabsf(v.z), fabsf(v.w)));
    #pragma unroll
    for (int m = 16; m >= 1; m >>= 1)
        amax = fmaxf(amax, __shfl_xor(amax, m));
    const float scale = fmaxf(amax, 1e-12f) / 448.0f;
    ushort4 o;
    o.x = f2bf(cast_e4m3(v.x / scale) * scale);
    o.y = f2bf(cast_e4m3(v.y / scale) * scale);
    o.z = f2bf(cast_e4m3(v.z / scale) * scale);
    o.w = f2bf(cast_e4m3(v.w / scale) * scale);
    *(ushort4*)&Xq[base] = o;
}

// w: 128x128 tiles. One 256-thread block per tile; values held in registers.
__global__ __launch_bounds__(256) void quant_w(const float* __restrict__ W,
                                               unsigned short* __restrict__ Wq) {
    const int tile = blockIdx.x;
    const int tr = tile >> 5;
    const int tc = tile & 31;
    const int t = threadIdx.x;
    const int c4 = (t & 31) * 4;
    const float* base = W + (size_t)(tr * 128) * K_DIM + tc * 128;

    float4 v[16];
    float amax = 0.0f;
    #pragma unroll
    for (int p = 0; p < 16; ++p) {
        const int r = p * 8 + (t >> 5);
        v[p] = *(const float4*)&base[(size_t)r * K_DIM + c4];
        amax = fmaxf(amax, fmaxf(fmaxf(fabsf(v[p].x), fabsf(v[p].y)),
                                 fabsf(fmaxf(fabsf(v[p].z), fabsf(v[p].w)))));
    }
    #pragma unroll
    for (int m = 32; m >= 1; m >>= 1)
        amax = fmaxf(amax, __shfl_xor(amax, m));
    __shared__ float red[4];
    if ((t & 63) == 0) red[t >> 6] = amax;
    __syncthreads();
    const float am4 = fmaxf(fmaxf(red[0], red[1]), fmaxf(red[2], red[3]));
    const float scale = fmaxf(am4, 1e-12f) / 448.0f;

    unsigned short* out = Wq + (size_t)(tr * 128) * K_DIM + tc * 128;
    #pragma unroll
    for (int p = 0; p < 16; ++p) {
        const int r = p * 8 + (t >> 5);
        ushort4 o;
        o.x = f2bf(cast_e4m3(v[p].x / scale) * scale);
        o.y = f2bf(cast_e4m3(v[p].y / scale) * scale);
        o.z = f2bf(cast_e4m3(v[p].z / scale) * scale);
        o.w = f2bf(cast_e4m3(v[p].w / scale) * scale);
        *(ushort4*)&out[(size_t)r * K_DIM + c4] = o;
    }
}

#define GLOAD16(g, l)                                                          \
    __builtin_amdgcn_global_load_lds(                                          \
        (const __attribute__((address_space(1))) void*)(g),                    \
        (__attribute__((address_space(3))) void*)(l), 16, 0, 0)

// ===================== 256x256 8-phase GEMM, BK=64, 8 waves =====================
// C[M,N] = A[M,K] * B[N,K]^T + bias.  LDS element bases:
//   A buf0: 0      A buf1: 16384   B buf0: 32768   B buf1: 49152   (x2B = 128KiB)
// Tiles: even K-tile -> buf0, odd -> buf1 (fixed, no flip).
// Stage ledger (iteration computes tile u @P1-4, u+1 @P5-8):
//   P1:A0(u+1)  P2:A1(u+1)  P3:B0(u+2)  P4:B1(u+2)+vmcnt(4)
//   P5:A0(u+2)  P6:A1(u+2)  P7:B0(u+3)  P8:B1(u+3)+vmcnt(4)
// Deadness: B-halves of a buf last read at P2/P6; A-halves at P3/P7 — every
// stage lands in a region >=2 barriers past its last ds_read.
// Swizzle (st_16x32): element col ^= (row&4)?16:0, applied to global SOURCE
// at stage time (LDS dest linear, per m104/m173) and to ds_read col.

#define BARRIER() __builtin_amdgcn_s_barrier()
#define LGKM0() asm volatile("s_waitcnt lgkmcnt(0)" ::: "memory")
#define LGKM8() asm volatile("s_waitcnt lgkmcnt(8)" ::: "memory")
#define VM4()   asm volatile("s_waitcnt vmcnt(4)" ::: "memory")
#define VM0()   asm volatile("s_waitcnt vmcnt(0)" ::: "memory")

#define STAGE(G, grow0, kt, ebase, ht) do {                                    \
    const unsigned short* _s0 = (G) +                                          \
        (size_t)((grow0) + (ht) * 128 + w * 8 + sr) * K_DIM + (kt) * 64 + src_col; \
    const unsigned short* _s1 = _s0 + (size_t)64 * K_DIM;                      \
    char* _lb = (char*)lds + (ebase) * 2 + ((ht) * 128 + w * 8) * 128;         \
    GLOAD16(_s0, _lb);                                                         \
    GLOAD16(_s1, _lb + 8192);                                                  \
} while (0)

#define LDA(mh, ebase) do {                                                    \
    _Pragma("unroll") for (int _m = 0; _m < 4; ++_m) {                         \
        const int _row = wm * 128 + (mh) * 64 + _m * 16 + lr;                  \
        a[_m][0] = *(const bf16x8*)&lds[(ebase) + _row * 64 + ((0  + hk) ^ rsw)]; \
        a[_m][1] = *(const bf16x8*)&lds[(ebase) + _row * 64 + ((32 + hk) ^ rsw)]; \
    }                                                                          \
} while (0)

#define LDB(nh, dst, ebase) do {                                               \
    _Pragma("unroll") for (int _n = 0; _n < 2; ++_n) {                         \
        const int _row = wn * 64 + (nh) * 32 + _n * 16 + lr;                   \
        dst[_n][0] = *(const bf16x8*)&lds[(ebase) + _row * 64 + ((0  + hk) ^ rsw)]; \
        dst[_n][1] = *(const bf16x8*)&lds[(ebase) + _row * 64 + ((32 + hk) ^ rsw)]; \
    }                                                                          \
} while (0)

#define MMA(mh, nh, bb) do {                                                   \
    _Pragma("unroll") for (int _m = 0; _m < 4; ++_m)                           \
    _Pragma("unroll") for (int _n = 0; _n < 2; ++_n)                           \
    _Pragma("unroll") for (int _k = 0; _k < 2; ++_k)                           \
        acc[(mh) * 4 + _m][(nh) * 2 + _n] =                                    \
            __builtin_amdgcn_mfma_f32_16x16x32_bf16(                           \
                a[_m][_k], bb[_n][_k], acc[(mh) * 4 + _m][(nh) * 2 + _n], 0, 0, 0); \
} while (0)

__global__ __launch_bounds__(512, 2) void gemm256(const unsigned short* __restrict__ A,
                                                  const unsigned short* __restrict__ B,
                                                  const float* __restrict__ bias,
                                                  float* __restrict__ C) {
    __shared__ __align__(16) unsigned short lds[65536];   // 128 KiB

    const int t = threadIdx.x;
    const int lane = t & 63;
    const int w = t >> 6;                 // 0..7
    const int wm = w >> 2, wn = w & 3;    // 2M x 4N wave grid

    int bid = blockIdx.x;
    bid = (bid & 7) * 64 + (bid >> 3);    // 512 blocks, %8==0 -> bijective
    const int bm = bid >> 4, bn = bid & 15;
    const size_t brow = (size_t)bm * 256, bcol = (size_t)bn * 256;

    // stage-side lane constants (inverse-swizzled global source col)
    const int sr = lane >> 3;                                  // row-in-8
    const int src_col = ((lane & 7) * 8) ^ ((lane & 32) ? 16 : 0);
    // read-side lane constants
    const int lr = lane & 15;
    const int hk = (lane >> 4) * 8;
    const int rsw = (lane & 4) << 2;                           // col ^= (row&4)?16:0

    f32x4 acc[8][4] = {};
    bf16x8 a[4][2], b0[2][2], b1[2][2];

    // prologue: tile0 (A+B) -> buf0, tile1 B-halves -> buf1
    STAGE(A, brow, 0, 0, 0);     STAGE(A, brow, 0, 0, 1);
    STAGE(B, bcol, 0, 32768, 0); STAGE(B, bcol, 0, 32768, 1);
    STAGE(B, bcol, 1, 49152, 0); STAGE(B, bcol, 1, 49152, 1);
    VM4(); BARRIER();

    for (int u = 0; u < 62; u += 2) {
        // P1: quad(0,0) of tile u
        LDA(0, 0); LDB(0, b0, 32768);
        STAGE(A, brow, u + 1, 16384, 0);
        LGKM8();
        BARRIER(); LGKM0();
        __builtin_amdgcn_s_setprio(1); MMA(0, 0, b0); __builtin_amdgcn_s_setprio(0);
        BARRIER();
        // P2: quad(0,1)
        LDB(1, b1, 32768);
        STAGE(A, brow, u + 1, 16384, 1);
        BARRIER(); LGKM0();
        __builtin_amdgcn_s_setprio(1); MMA(0, 1, b1); __builtin_amdgcn_s_setprio(0);
        BARRIER();
        // P3: quad(1,1)
        LDA(1, 0);
        STAGE(B, bcol, u + 2, 32768, 0);
        BARRIER(); LGKM0();
        __builtin_amdgcn_s_setprio(1); MMA(1, 1, b1); __builtin_amdgcn_s_setprio(0);
        BARRIER();
        // P4: quad(1,0), K-tile boundary wait
        STAGE(B, bcol, u + 2, 32768, 1);
        BARRIER();
        __builtin_amdgcn_s_setprio(1); MMA(1, 0, b0); __builtin_amdgcn_s_setprio(0);
        VM4();
        BARRIER();
        // P5: quad(0,0) of tile u+1
        LDA(0, 16384); LDB(0, b0, 49152);
        STAGE(A, brow, u + 2, 0, 0);
        LGKM8();
        BARRIER(); LGKM0();
        __builtin_amdgcn_s_setprio(1); MMA(0, 0, b0); __builtin_amdgcn_s_setprio(0);
        BARRIER();
        // P6: quad(0,1)
        LDB(1, b1, 49152);
        STAGE(A, brow, u + 2, 0, 1);
        BARRIER(); LGKM0();
        __builtin_amdgcn_s_setprio(1); MMA(0, 1, b1); __builtin_amdgcn_s_setprio(0);
        BARRIER();
        // P7: quad(1,1)
        LDA(1, 16384);
        STAGE(B, bcol, u + 3, 49152, 0);
        BARRIER(); LGKM0();
        __builtin_amdgcn_s_setprio(1); MMA(1, 1, b1); __builtin_amdgcn_s_setprio(0);
        BARRIER();
        // P8: quad(1,0), K-tile boundary wait
        STAGE(B, bcol, u + 3, 49152, 1);
        BARRIER();
        __builtin_amdgcn_s_setprio(1); MMA(1, 0, b0); __builtin_amdgcn_s_setprio(0);
        VM4();
        BARRIER();
    }

    // epilogue: tiles 62 (buf0) and 63 (buf1); A(63) still staged at P1/P2
    LDA(0, 0); LDB(0, b0, 32768);
    STAGE(A, brow, 63, 16384, 0);
    BARRIER(); LGKM0(); MMA(0, 0, b0); BARRIER();

    LDB(1, b1, 32768);
    STAGE(A, brow, 63, 16384, 1);
    BARRIER(); LGKM0(); MMA(0, 1, b1); BARRIER();

    LDA(1, 0);
    BARRIER(); LGKM0(); MMA(1, 1, b1); BARRIER();

    BARRIER(); MMA(1, 0, b0); VM0(); BARRIER();

    LDA(0, 16384); LDB(0, b0, 49152);
    BARRIER(); LGKM0(); MMA(0, 0, b0); BARRIER();

    LDB(1, b1, 49152);
    BARRIER(); LGKM0(); MMA(0, 1, b1); BARRIER();

    LDA(1, 16384);
    BARRIER(); LGKM0(); MMA(1, 1, b1); BARRIER();

    MMA(1, 0, b0);

    // C write: acc[i][j] -> row = wm*128 + i*16 + (lane>>4)*4 + jj, col = wn*64 + j*16 + (lane&15)
    #pragma unroll
    for (int i = 0; i < 8; ++i) {
        const size_t row_base = brow + wm * 128 + i * 16 + (lane >> 4) * 4;
        #pragma unroll
        for (int j = 0; j < 4; ++j) {
            const size_t col = bcol + wn * 64 + j * 16 + lr;
            const float bv = bias[col];
            #pragma unroll
            for (int jj = 0; jj < 4; ++jj)
                C[(row_base + jj) * (size_t)N_DIM + col] = acc[i][j][jj] + bv;
        }
    }
}

extern "C" void kernel_launch(void* const* d_in, const int* in_sizes, int n_in,
                              void* d_out, int out_size, void* d_ws, size_t ws_size,
                              hipStream_t stream) {
    const float* x = (const float*)d_in[0];
    const float* w = (const float*)d_in[1];
    const float* bias = (const float*)d_in[2];
    float* out = (float*)d_out;

    unsigned short* xq = (unsigned short*)d_ws;
    unsigned short* wq = xq + (size_t)M_DIM * K_DIM;

    quant_x<<<(M_DIM * (K_DIM / 128)) / 8, 256, 0, stream>>>(x, xq);
    quant_w<<<(N_DIM / 128) * (K_DIM / 128), 256, 0, stream>>>(w, wq);
    gemm256<<<(M_DIM / 256) * (N_DIM / 256), 512, 0, stream>>>(xq, wq, bias, out);
}

// Round 3
// 308.356 us; speedup vs baseline: 1.3772x; 1.0010x over previous
//
#include <hip/hip_runtime.h>

#define M_DIM 8192
#define N_DIM 4096
#define K_DIM 4096

typedef __bf16 bf16x8 __attribute__((ext_vector_type(8)));
typedef float f32x4 __attribute__((ext_vector_type(4)));

// bf16 round-to-nearest-even from fp32 (no NaN in this problem)
__device__ __forceinline__ unsigned short f2bf(float f) {
    unsigned u = __float_as_uint(f);
    u += 0x7FFFu + ((u >> 16) & 1u);
    return (unsigned short)(u >> 16);
}

// Bit-exact replica of reference _cast_e4m3 (round-half-even, subnormals, sat 448)
__device__ __forceinline__ float cast_e4m3(float v) {
    float a = fminf(fabsf(v), 448.0f);
    float am = fmaxf(a, 0x1p-9f);
    int e = (int)((__float_as_uint(am) >> 23) & 0xFFu) - 127;   // floor(log2(am)), exact
    e = (e < -6) ? -6 : e;
    float step = __uint_as_float((unsigned)(e - 3 + 127) << 23); // 2^(e-3)
    float q = rintf(a / step) * step;                            // a/step exact, RNE tie
    q = fminf(q, 448.0f);
    return (v < 0.0f) ? -q : q;
}

// x: per-row 1x128 blocks. One 32-lane group per block, 4 floats/lane.
__global__ __launch_bounds__(256) void quant_x(const float* __restrict__ X,
                                               unsigned short* __restrict__ Xq) {
    const int g = threadIdx.x >> 5;
    const int l = threadIdx.x & 31;
    const long rb = (long)blockIdx.x * 8 + g;
    const int row = (int)(rb >> 5);
    const int kb = (int)(rb & 31);
    const size_t base = (size_t)row * K_DIM + kb * 128 + l * 4;
    const float4 v = *(const float4*)&X[base];
    float amax = fmaxf(fmaxf(fabsf(v.x), fabsf(v.y)), fmaxf(fabsf(v.z), fabsf(v.w)));
    #pragma unroll
    for (int m = 16; m >= 1; m >>= 1)
        amax = fmaxf(amax, __shfl_xor(amax, m));
    const float scale = fmaxf(amax, 1e-12f) / 448.0f;
    ushort4 o;
    o.x = f2bf(cast_e4m3(v.x / scale) * scale);
    o.y = f2bf(cast_e4m3(v.y / scale) * scale);
    o.z = f2bf(cast_e4m3(v.z / scale) * scale);
    o.w = f2bf(cast_e4m3(v.w / scale) * scale);
    *(ushort4*)&Xq[base] = o;
}

// w: 128x128 tiles. One 256-thread block per tile; values held in registers.
__global__ __launch_bounds__(256) void quant_w(const float* __restrict__ W,
                                               unsigned short* __restrict__ Wq) {
    const int tile = blockIdx.x;
    const int tr = tile >> 5;
    const int tc = tile & 31;
    const int t = threadIdx.x;
    const int c4 = (t & 31) * 4;
    const float* base = W + (size_t)(tr * 128) * K_DIM + tc * 128;

    float4 v[16];
    float amax = 0.0f;
    #pragma unroll
    for (int p = 0; p < 16; ++p) {
        const int r = p * 8 + (t >> 5);
        v[p] = *(const float4*)&base[(size_t)r * K_DIM + c4];
        amax = fmaxf(amax, fmaxf(fmaxf(fabsf(v[p].x), fabsf(v[p].y)),
                                 fmaxf(fabsf(v[p].z), fabsf(v[p].w))));
    }
    #pragma unroll
    for (int m = 32; m >= 1; m >>= 1)
        amax = fmaxf(amax, __shfl_xor(amax, m));
    __shared__ float red[4];
    if ((t & 63) == 0) red[t >> 6] = amax;
    __syncthreads();
    const float am4 = fmaxf(fmaxf(red[0], red[1]), fmaxf(red[2], red[3]));
    const float scale = fmaxf(am4, 1e-12f) / 448.0f;

    unsigned short* out = Wq + (size_t)(tr * 128) * K_DIM + tc * 128;
    #pragma unroll
    for (int p = 0; p < 16; ++p) {
        const int r = p * 8 + (t >> 5);
        ushort4 o;
        o.x = f2bf(cast_e4m3(v[p].x / scale) * scale);
        o.y = f2bf(cast_e4m3(v[p].y / scale) * scale);
        o.z = f2bf(cast_e4m3(v[p].z / scale) * scale);
        o.w = f2bf(cast_e4m3(v[p].w / scale) * scale);
        *(ushort4*)&out[(size_t)r * K_DIM + c4] = o;
    }
}

#define GLOAD16(g, l)                                                          \
    __builtin_amdgcn_global_load_lds(                                          \
        (const __attribute__((address_space(1))) void*)(g),                    \
        (__attribute__((address_space(3))) void*)(l), 16, 0, 0)

// ===================== 256x256 8-phase GEMM, BK=64, 8 waves =====================
// C[M,N] = A[M,K] * B[N,K]^T + bias.  LDS element bases:
//   A buf0: 0      A buf1: 16384   B buf0: 32768   B buf1: 49152   (x2B = 128KiB)
// Tiles: even K-tile -> buf0, odd -> buf1 (fixed, no flip).
// Stage ledger (iteration computes tile u @P1-4, u+1 @P5-8):
//   P1:A0(u+1)  P2:A1(u+1)  P3:B0(u+2)  P4:B1(u+2)+vmcnt(4)
//   P5:A0(u+2)  P6:A1(u+2)  P7:B0(u+3)  P8:B1(u+3)+vmcnt(4)
// Deadness: B-halves of a buf last read at P2/P6; A-halves at P3/P7 — every
// stage lands in a region >=2 barriers past its last ds_read.
// Swizzle (2-bit, derived R3): element col ^= (row&12)<<2, i.e. rows 0-3:+0,
// 4-7:^16, 8-11:^32, 12-15:^48. A 16-lane row-group's ds_read_b128 then puts
// exactly 8 dwords on every bank (the b128 minimum) instead of 16 on half the
// banks. Applied to global SOURCE at stage time (LDS dest linear, m104/m173)
// and to ds_read col: row bit2 = lane bit5, row bit3 = wave bit0 at stage.

#define BARRIER() __builtin_amdgcn_s_barrier()
#define LGKM0() asm volatile("s_waitcnt lgkmcnt(0)" ::: "memory")
#define LGKM8() asm volatile("s_waitcnt lgkmcnt(8)" ::: "memory")
#define VM4()   asm volatile("s_waitcnt vmcnt(4)" ::: "memory")
#define VM0()   asm volatile("s_waitcnt vmcnt(0)" ::: "memory")

#define STAGE(G, grow0, kt, ebase, ht) do {                                    \
    const unsigned short* _s0 = (G) +                                          \
        (size_t)((grow0) + (ht) * 128 + w * 8 + sr) * K_DIM + (kt) * 64 + src_col; \
    const unsigned short* _s1 = _s0 + (size_t)64 * K_DIM;                      \
    char* _lb = (char*)lds + (ebase) * 2 + ((ht) * 128 + w * 8) * 128;         \
    GLOAD16(_s0, _lb);                                                         \
    GLOAD16(_s1, _lb + 8192);                                                  \
} while (0)

#define LDA(mh, ebase) do {                                                    \
    _Pragma("unroll") for (int _m = 0; _m < 4; ++_m) {                         \
        const int _row = wm * 128 + (mh) * 64 + _m * 16 + lr;                  \
        a[_m][0] = *(const bf16x8*)&lds[(ebase) + _row * 64 + ((0  + hk) ^ rsw)]; \
        a[_m][1] = *(const bf16x8*)&lds[(ebase) + _row * 64 + ((32 + hk) ^ rsw)]; \
    }                                                                          \
} while (0)

#define LDB(nh, dst, ebase) do {                                               \
    _Pragma("unroll") for (int _n = 0; _n < 2; ++_n) {                         \
        const int _row = wn * 64 + (nh) * 32 + _n * 16 + lr;                   \
        dst[_n][0] = *(const bf16x8*)&lds[(ebase) + _row * 64 + ((0  + hk) ^ rsw)]; \
        dst[_n][1] = *(const bf16x8*)&lds[(ebase) + _row * 64 + ((32 + hk) ^ rsw)]; \
    }                                                                          \
} while (0)

#define MMA(mh, nh, bb) do {                                                   \
    _Pragma("unroll") for (int _m = 0; _m < 4; ++_m)                           \
    _Pragma("unroll") for (int _n = 0; _n < 2; ++_n)                           \
    _Pragma("unroll") for (int _k = 0; _k < 2; ++_k)                           \
        acc[(mh) * 4 + _m][(nh) * 2 + _n] =                                    \
            __builtin_amdgcn_mfma_f32_16x16x32_bf16(                           \
                a[_m][_k], bb[_n][_k], acc[(mh) * 4 + _m][(nh) * 2 + _n], 0, 0, 0); \
} while (0)

__global__ __launch_bounds__(512, 2) void gemm256(const unsigned short* __restrict__ A,
                                                  const unsigned short* __restrict__ B,
                                                  const float* __restrict__ bias,
                                                  float* __restrict__ C) {
    __shared__ __align__(16) unsigned short lds[65536];   // 128 KiB

    const int t = threadIdx.x;
    const int lane = t & 63;
    const int w = t >> 6;                 // 0..7
    const int wm = w >> 2, wn = w & 3;    // 2M x 4N wave grid

    int bid = blockIdx.x;
    bid = (bid & 7) * 64 + (bid >> 3);    // 512 blocks, %8==0 -> bijective
    const int bm = bid >> 4, bn = bid & 15;
    const size_t brow = (size_t)bm * 256, bcol = (size_t)bn * 256;

    // stage-side lane constants (inverse-swizzled global source col)
    const int sr = lane >> 3;                                  // row-in-8
    const int src_col = ((lane & 7) * 8) ^ ((lane & 32) ? 16 : 0)
                                         ^ ((w & 1) ? 32 : 0);
    // read-side lane constants
    const int lr = lane & 15;
    const int hk = (lane >> 4) * 8;
    const int rsw = (lane & 12) << 2;     // col ^= {0,16,32,48} by row bits 2-3

    f32x4 acc[8][4] = {};
    bf16x8 a[4][2], b0[2][2], b1[2][2];

    // prologue: tile0 (A+B) -> buf0, tile1 B-halves -> buf1
    STAGE(A, brow, 0, 0, 0);     STAGE(A, brow, 0, 0, 1);
    STAGE(B, bcol, 0, 32768, 0); STAGE(B, bcol, 0, 32768, 1);
    STAGE(B, bcol, 1, 49152, 0); STAGE(B, bcol, 1, 49152, 1);
    VM4(); BARRIER();

    for (int u = 0; u < 62; u += 2) {
        // P1: quad(0,0) of tile u
        LDA(0, 0); LDB(0, b0, 32768);
        STAGE(A, brow, u + 1, 16384, 0);
        LGKM8();
        BARRIER(); LGKM0();
        __builtin_amdgcn_s_setprio(1); MMA(0, 0, b0); __builtin_amdgcn_s_setprio(0);
        BARRIER();
        // P2: quad(0,1)
        LDB(1, b1, 32768);
        STAGE(A, brow, u + 1, 16384, 1);
        BARRIER(); LGKM0();
        __builtin_amdgcn_s_setprio(1); MMA(0, 1, b1); __builtin_amdgcn_s_setprio(0);
        BARRIER();
        // P3: quad(1,1)
        LDA(1, 0);
        STAGE(B, bcol, u + 2, 32768, 0);
        BARRIER(); LGKM0();
        __builtin_amdgcn_s_setprio(1); MMA(1, 1, b1); __builtin_amdgcn_s_setprio(0);
        BARRIER();
        // P4: quad(1,0), K-tile boundary wait
        STAGE(B, bcol, u + 2, 32768, 1);
        BARRIER();
        __builtin_amdgcn_s_setprio(1); MMA(1, 0, b0); __builtin_amdgcn_s_setprio(0);
        VM4();
        BARRIER();
        // P5: quad(0,0) of tile u+1
        LDA(0, 16384); LDB(0, b0, 49152);
        STAGE(A, brow, u + 2, 0, 0);
        LGKM8();
        BARRIER(); LGKM0();
        __builtin_amdgcn_s_setprio(1); MMA(0, 0, b0); __builtin_amdgcn_s_setprio(0);
        BARRIER();
        // P6: quad(0,1)
        LDB(1, b1, 49152);
        STAGE(A, brow, u + 2, 0, 1);
        BARRIER(); LGKM0();
        __builtin_amdgcn_s_setprio(1); MMA(0, 1, b1); __builtin_amdgcn_s_setprio(0);
        BARRIER();
        // P7: quad(1,1)
        LDA(1, 16384);
        STAGE(B, bcol, u + 3, 49152, 0);
        BARRIER(); LGKM0();
        __builtin_amdgcn_s_setprio(1); MMA(1, 1, b1); __builtin_amdgcn_s_setprio(0);
        BARRIER();
        // P8: quad(1,0), K-tile boundary wait
        STAGE(B, bcol, u + 3, 49152, 1);
        BARRIER();
        __builtin_amdgcn_s_setprio(1); MMA(1, 0, b0); __builtin_amdgcn_s_setprio(0);
        VM4();
        BARRIER();
    }

    // epilogue: tiles 62 (buf0) and 63 (buf1); A(63) still staged at P1/P2
    LDA(0, 0); LDB(0, b0, 32768);
    STAGE(A, brow, 63, 16384, 0);
    BARRIER(); LGKM0(); MMA(0, 0, b0); BARRIER();

    LDB(1, b1, 32768);
    STAGE(A, brow, 63, 16384, 1);
    BARRIER(); LGKM0(); MMA(0, 1, b1); BARRIER();

    LDA(1, 0);
    BARRIER(); LGKM0(); MMA(1, 1, b1); BARRIER();

    BARRIER(); MMA(1, 0, b0); VM0(); BARRIER();

    LDA(0, 16384); LDB(0, b0, 49152);
    BARRIER(); LGKM0(); MMA(0, 0, b0); BARRIER();

    LDB(1, b1, 49152);
    BARRIER(); LGKM0(); MMA(0, 1, b1); BARRIER();

    LDA(1, 16384);
    BARRIER(); LGKM0(); MMA(1, 1, b1); BARRIER();

    MMA(1, 0, b0);

    // C write: acc[i][j] -> row = wm*128 + i*16 + (lane>>4)*4 + jj, col = wn*64 + j*16 + (lane&15)
    #pragma unroll
    for (int i = 0; i < 8; ++i) {
        const size_t row_base = brow + wm * 128 + i * 16 + (lane >> 4) * 4;
        #pragma unroll
        for (int j = 0; j < 4; ++j) {
            const size_t col = bcol + wn * 64 + j * 16 + lr;
            const float bv = bias[col];
            #pragma unroll
            for (int jj = 0; jj < 4; ++jj)
                C[(row_base + jj) * (size_t)N_DIM + col] = acc[i][j][jj] + bv;
        }
    }
}

extern "C" void kernel_launch(void* const* d_in, const int* in_sizes, int n_in,
                              void* d_out, int out_size, void* d_ws, size_t ws_size,
                              hipStream_t stream) {
    const float* x = (const float*)d_in[0];
    const float* w = (const float*)d_in[1];
    const float* bias = (const float*)d_in[2];
    float* out = (float*)d_out;

    unsigned short* xq = (unsigned short*)d_ws;
    unsigned short* wq = xq + (size_t)M_DIM * K_DIM;

    quant_x<<<(M_DIM * (K_DIM / 128)) / 8, 256, 0, stream>>>(x, xq);
    quant_w<<<(N_DIM / 128) * (K_DIM / 128), 256, 0, stream>>>(w, wq);
    gemm256<<<(M_DIM / 256) * (N_DIM / 256), 512, 0, stream>>>(xq, wq, bias, out);
}

// Round 5
// 292.117 us; speedup vs baseline: 1.4537x; 1.0556x over previous
//
#include <hip/hip_runtime.h>

#define M_DIM 8192
#define N_DIM 4096
#define K_DIM 4096

typedef __bf16 bf16x8 __attribute__((ext_vector_type(8)));
typedef float f32x4 __attribute__((ext_vector_type(4)));

// bf16 round-to-nearest-even from fp32 (no NaN in this problem)
__device__ __forceinline__ unsigned short f2bf(float f) {
    unsigned u = __float_as_uint(f);
    u += 0x7FFFu + ((u >> 16) & 1u);
    return (unsigned short)(u >> 16);
}

// Bit-exact replica of reference _cast_e4m3 (round-half-even, subnormals, sat 448)
__device__ __forceinline__ float cast_e4m3(float v) {
    float a = fminf(fabsf(v), 448.0f);
    float am = fmaxf(a, 0x1p-9f);
    int e = (int)((__float_as_uint(am) >> 23) & 0xFFu) - 127;   // floor(log2(am)), exact
    e = (e < -6) ? -6 : e;
    float step = __uint_as_float((unsigned)(e - 3 + 127) << 23); // 2^(e-3)
    float q = rintf(a / step) * step;                            // a/step exact, RNE tie
    q = fminf(q, 448.0f);
    return (v < 0.0f) ? -q : q;
}

// x: per-row 1x128 blocks. One 32-lane group per block, 4 floats/lane.
__global__ __launch_bounds__(256) void quant_x(const float* __restrict__ X,
                                               unsigned short* __restrict__ Xq) {
    const int g = threadIdx.x >> 5;
    const int l = threadIdx.x & 31;
    const long rb = (long)blockIdx.x * 8 + g;
    const int row = (int)(rb >> 5);
    const int kb = (int)(rb & 31);
    const size_t base = (size_t)row * K_DIM + kb * 128 + l * 4;
    const float4 v = *(const float4*)&X[base];
    float amax = fmaxf(fmaxf(fabsf(v.x), fabsf(v.y)), fmaxf(fabsf(v.z), fabsf(v.w)));
    #pragma unroll
    for (int m = 16; m >= 1; m >>= 1)
        amax = fmaxf(amax, __shfl_xor(amax, m));
    const float scale = fmaxf(amax, 1e-12f) / 448.0f;
    ushort4 o;
    o.x = f2bf(cast_e4m3(v.x / scale) * scale);
    o.y = f2bf(cast_e4m3(v.y / scale) * scale);
    o.z = f2bf(cast_e4m3(v.z / scale) * scale);
    o.w = f2bf(cast_e4m3(v.w / scale) * scale);
    *(ushort4*)&Xq[base] = o;
}

// w: 128x128 tiles. One 256-thread block per tile; values held in registers.
__global__ __launch_bounds__(256) void quant_w(const float* __restrict__ W,
                                               unsigned short* __restrict__ Wq) {
    const int tile = blockIdx.x;
    const int tr = tile >> 5;
    const int tc = tile & 31;
    const int t = threadIdx.x;
    const int c4 = (t & 31) * 4;
    const float* base = W + (size_t)(tr * 128) * K_DIM + tc * 128;

    float4 v[16];
    float amax = 0.0f;
    #pragma unroll
    for (int p = 0; p < 16; ++p) {
        const int r = p * 8 + (t >> 5);
        v[p] = *(const float4*)&base[(size_t)r * K_DIM + c4];
        amax = fmaxf(amax, fmaxf(fmaxf(fabsf(v[p].x), fabsf(v[p].y)),
                                 fmaxf(fabsf(v[p].z), fabsf(v[p].w))));
    }
    #pragma unroll
    for (int m = 32; m >= 1; m >>= 1)
        amax = fmaxf(amax, __shfl_xor(amax, m));
    __shared__ float red[4];
    if ((t & 63) == 0) red[t >> 6] = amax;
    __syncthreads();
    const float am4 = fmaxf(fmaxf(red[0], red[1]), fmaxf(red[2], red[3]));
    const float scale = fmaxf(am4, 1e-12f) / 448.0f;

    unsigned short* out = Wq + (size_t)(tr * 128) * K_DIM + tc * 128;
    #pragma unroll
    for (int p = 0; p < 16; ++p) {
        const int r = p * 8 + (t >> 5);
        ushort4 o;
        o.x = f2bf(cast_e4m3(v[p].x / scale) * scale);
        o.y = f2bf(cast_e4m3(v[p].y / scale) * scale);
        o.z = f2bf(cast_e4m3(v[p].z / scale) * scale);
        o.w = f2bf(cast_e4m3(v[p].w / scale) * scale);
        *(ushort4*)&out[(size_t)r * K_DIM + c4] = o;
    }
}

#define GLOAD16(g, l)                                                          \
    __builtin_amdgcn_global_load_lds(                                          \
        (const __attribute__((address_space(1))) void*)(g),                    \
        (__attribute__((address_space(3))) void*)(l), 16, 0, 0)

// ===================== 256x256 8-phase GEMM, BK=64, 8 waves =====================
// C[M,N] = A[M,K] * B[N,K]^T + bias.  LDS element bases:
//   A buf0: 0      A buf1: 16384   B buf0: 32768   B buf1: 49152   (x2B = 128KiB)
// Tiles: even K-tile -> buf0, odd -> buf1 (fixed, no flip).
// Stage ledger (iteration computes tile u @P1-4, u+1 @P5-8):
//   P1:A0(u+1)  P2:A1(u+1)  P3:B0(u+2)  P4:B1(u+2)+vmcnt(4)
//   P5:A0(u+2)  P6:A1(u+2)  P7:B0(u+3)  P8:B1(u+3)+vmcnt(4)
// vmcnt(4) at P4/P8 is the max safe depth for THIS ledger: at the P4 wait the
// only stages not yet needed are B(u+2) = 2 calls = 4 loads; anything deeper
// leaves A1(u+1) in flight past P5's read (the R4 race — tripwire-confirmed).
// Swizzle (3-bit on row bits 0-2): LDS[row][c] holds logical element
// (row, c ^ ((row&7)<<3)). Bank model: bank depends only on col (row stride
// 128B); b128 issues in 8-lane groups needing 8 distinct 16B bank-quads.
// Rows 0-7 sit in one 8-lane group -> XOR of row bits 0-2 into col bits 3-5
// gives all 8 quads (R2/R3's row-bit>=2 XORs gave only 2 -> the frozen 4x
// conflict counter). Stage-side: linear LDS dest (m104), inverse-permuted
// global source col = ((lane&7) ^ ((lane>>3)&7))<<3  (stage row bits 0-2 =
// lane>>3; involution verified + absmax-validated in R4).

#define BARRIER() __builtin_amdgcn_s_barrier()
#define LGKM0() asm volatile("s_waitcnt lgkmcnt(0)" ::: "memory")
#define LGKM8() asm volatile("s_waitcnt lgkmcnt(8)" ::: "memory")
#define VM4()   asm volatile("s_waitcnt vmcnt(4)" ::: "memory")
#define VM0()   asm volatile("s_waitcnt vmcnt(0)" ::: "memory")

#define STAGE(G, grow0, kt, ebase, ht) do {                                    \
    const unsigned short* _s0 = (G) +                                          \
        (size_t)((grow0) + (ht) * 128 + w * 8 + sr) * K_DIM + (kt) * 64 + src_col; \
    const unsigned short* _s1 = _s0 + (size_t)64 * K_DIM;                      \
    char* _lb = (char*)lds + (ebase) * 2 + ((ht) * 128 + w * 8) * 128;         \
    GLOAD16(_s0, _lb);                                                         \
    GLOAD16(_s1, _lb + 8192);                                                  \
} while (0)

#define LDA(mh, ebase) do {                                                    \
    _Pragma("unroll") for (int _m = 0; _m < 4; ++_m) {                         \
        const int _row = wm * 128 + (mh) * 64 + _m * 16 + lr;                  \
        a[_m][0] = *(const bf16x8*)&lds[(ebase) + _row * 64 + ((0  + hk) ^ rsw)]; \
        a[_m][1] = *(const bf16x8*)&lds[(ebase) + _row * 64 + ((32 + hk) ^ rsw)]; \
    }                                                                          \
} while (0)

#define LDB(nh, dst, ebase) do {                                               \
    _Pragma("unroll") for (int _n = 0; _n < 2; ++_n) {                         \
        const int _row = wn * 64 + (nh) * 32 + _n * 16 + lr;                   \
        dst[_n][0] = *(const bf16x8*)&lds[(ebase) + _row * 64 + ((0  + hk) ^ rsw)]; \
        dst[_n][1] = *(const bf16x8*)&lds[(ebase) + _row * 64 + ((32 + hk) ^ rsw)]; \
    }                                                                          \
} while (0)

#define MMA(mh, nh, bb) do {                                                   \
    _Pragma("unroll") for (int _m = 0; _m < 4; ++_m)                           \
    _Pragma("unroll") for (int _n = 0; _n < 2; ++_n)                           \
    _Pragma("unroll") for (int _k = 0; _k < 2; ++_k)                           \
        acc[(mh) * 4 + _m][(nh) * 2 + _n] =                                    \
            __builtin_amdgcn_mfma_f32_16x16x32_bf16(                           \
                a[_m][_k], bb[_n][_k], acc[(mh) * 4 + _m][(nh) * 2 + _n], 0, 0, 0); \
} while (0)

__global__ __launch_bounds__(512, 2) void gemm256(const unsigned short* __restrict__ A,
                                                  const unsigned short* __restrict__ B,
                                                  const float* __restrict__ bias,
                                                  float* __restrict__ C) {
    __shared__ __align__(16) unsigned short lds[65536];   // 128 KiB

    const int t = threadIdx.x;
    const int lane = t & 63;
    const int w = t >> 6;                 // 0..7
    const int wm = w >> 2, wn = w & 3;    // 2M x 4N wave grid

    int bid = blockIdx.x;
    bid = (bid & 7) * 64 + (bid >> 3);    // 512 blocks, %8==0 -> bijective
    const int bm = bid >> 4, bn = bid & 15;
    const size_t brow = (size_t)bm * 256, bcol = (size_t)bn * 256;

    // stage-side lane constants: row-in-8 = lane>>3; inverse-swizzled source col
    const int sr = lane >> 3;
    const int src_col = (((lane & 7) ^ ((lane >> 3) & 7)) << 3);
    // read-side lane constants
    const int lr = lane & 15;
    const int hk = (lane >> 4) * 8;
    const int rsw = (lane & 7) << 3;      // col ^= (row&7)<<3, row&7 == lr&7 == lane&7

    f32x4 acc[8][4] = {};
    bf16x8 a[4][2], b0[2][2], b1[2][2];

    // prologue: tile0 (A+B) -> buf0, tile1 B-halves -> buf1
    STAGE(A, brow, 0, 0, 0);     STAGE(A, brow, 0, 0, 1);
    STAGE(B, bcol, 0, 32768, 0); STAGE(B, bcol, 0, 32768, 1);
    STAGE(B, bcol, 1, 49152, 0); STAGE(B, bcol, 1, 49152, 1);
    VM4(); BARRIER();

    for (int u = 0; u < 62; u += 2) {
        // P1: quad(0,0) of tile u
        LDA(0, 0); LDB(0, b0, 32768);
        STAGE(A, brow, u + 1, 16384, 0);
        LGKM8();
        BARRIER(); LGKM0();
        __builtin_amdgcn_s_setprio(1); MMA(0, 0, b0); __builtin_amdgcn_s_setprio(0);
        BARRIER();
        // P2: quad(0,1)
        LDB(1, b1, 32768);
        STAGE(A, brow, u + 1, 16384, 1);
        BARRIER(); LGKM0();
        __builtin_amdgcn_s_setprio(1); MMA(0, 1, b1); __builtin_amdgcn_s_setprio(0);
        BARRIER();
        // P3: quad(1,1)
        LDA(1, 0);
        STAGE(B, bcol, u + 2, 32768, 0);
        BARRIER(); LGKM0();
        __builtin_amdgcn_s_setprio(1); MMA(1, 1, b1); __builtin_amdgcn_s_setprio(0);
        BARRIER();
        // P4: quad(1,0), K-tile boundary wait
        STAGE(B, bcol, u + 2, 32768, 1);
        BARRIER();
        __builtin_amdgcn_s_setprio(1); MMA(1, 0, b0); __builtin_amdgcn_s_setprio(0);
        VM4();
        BARRIER();
        // P5: quad(0,0) of tile u+1
        LDA(0, 16384); LDB(0, b0, 49152);
        STAGE(A, brow, u + 2, 0, 0);
        LGKM8();
        BARRIER(); LGKM0();
        __builtin_amdgcn_s_setprio(1); MMA(0, 0, b0); __builtin_amdgcn_s_setprio(0);
        BARRIER();
        // P6: quad(0,1)
        LDB(1, b1, 49152);
        STAGE(A, brow, u + 2, 0, 1);
        BARRIER(); LGKM0();
        __builtin_amdgcn_s_setprio(1); MMA(0, 1, b1); __builtin_amdgcn_s_setprio(0);
        BARRIER();
        // P7: quad(1,1)
        LDA(1, 16384);
        STAGE(B, bcol, u + 3, 49152, 0);
        BARRIER(); LGKM0();
        __builtin_amdgcn_s_setprio(1); MMA(1, 1, b1); __builtin_amdgcn_s_setprio(0);
        BARRIER();
        // P8: quad(1,0), K-tile boundary wait
        STAGE(B, bcol, u + 3, 49152, 1);
        BARRIER();
        __builtin_amdgcn_s_setprio(1); MMA(1, 0, b0); __builtin_amdgcn_s_setprio(0);
        VM4();
        BARRIER();
    }

    // epilogue: tiles 62 (buf0) and 63 (buf1); A(63) staged at ph1/ph2.
    // Post-loop outstanding (<=4): {B0(63), B1(63)} — all of tile 62 landed.
    LDA(0, 0); LDB(0, b0, 32768);
    STAGE(A, brow, 63, 16384, 0);
    BARRIER(); LGKM0(); MMA(0, 0, b0); BARRIER();

    LDB(1, b1, 32768);
    STAGE(A, brow, 63, 16384, 1);
    BARRIER(); LGKM0(); MMA(0, 1, b1); BARRIER();

    LDA(1, 0);
    BARRIER(); LGKM0(); MMA(1, 1, b1); BARRIER();

    BARRIER(); MMA(1, 0, b0); VM0(); BARRIER();   // drain A(63)/B(63) fully

    LDA(0, 16384); LDB(0, b0, 49152);
    BARRIER(); LGKM0(); MMA(0, 0, b0); BARRIER();

    LDB(1, b1, 49152);
    BARRIER(); LGKM0(); MMA(0, 1, b1); BARRIER();

    LDA(1, 16384);
    BARRIER(); LGKM0(); MMA(1, 1, b1); BARRIER();

    MMA(1, 0, b0);

    // C write: acc[i][j] -> row = wm*128 + i*16 + (lane>>4)*4 + jj, col = wn*64 + j*16 + (lane&15)
    #pragma unroll
    for (int i = 0; i < 8; ++i) {
        const size_t row_base = brow + wm * 128 + i * 16 + (lane >> 4) * 4;
        #pragma unroll
        for (int j = 0; j < 4; ++j) {
            const size_t col = bcol + wn * 64 + j * 16 + lr;
            const float bv = bias[col];
            #pragma unroll
            for (int jj = 0; jj < 4; ++jj)
                C[(row_base + jj) * (size_t)N_DIM + col] = acc[i][j][jj] + bv;
        }
    }
}

extern "C" void kernel_launch(void* const* d_in, const int* in_sizes, int n_in,
                              void* d_out, int out_size, void* d_ws, size_t ws_size,
                              hipStream_t stream) {
    const float* x = (const float*)d_in[0];
    const float* w = (const float*)d_in[1];
    const float* bias = (const float*)d_in[2];
    float* out = (float*)d_out;

    unsigned short* xq = (unsigned short*)d_ws;
    unsigned short* wq = xq + (size_t)M_DIM * K_DIM;

    quant_x<<<(M_DIM * (K_DIM / 128)) / 8, 256, 0, stream>>>(x, xq);
    quant_w<<<(N_DIM / 128) * (K_DIM / 128), 256, 0, stream>>>(w, wq);
    gemm256<<<(M_DIM / 256) * (N_DIM / 256), 512, 0, stream>>>(xq, wq, bias, out);
}